// Round 16
// baseline (4627.879 us; speedup 1.0000x reference)
//
#include <hip/hip_runtime.h>
#include <hip/hip_fp16.h>

namespace {

constexpr int kS  = 1024;   // SEQ
constexpr int kI  = 64;     // INPUT_SIZE
constexpr int kH  = 128;    // HIDDEN
constexpr int kTT = 16;     // steps per tile

// fp16 weight layout in d_ws (element offsets)
constexpr int oWx1 = 0;            // [512][64]
constexpr int oWh1 = 32768;        // [512][128]
constexpr int oWx2 = 98304;        // [512][128]
constexpr int oWh2 = 163840;       // [512][128]
constexpr int nW   = 229376;

typedef _Float16 f16x8 __attribute__((ext_vector_type(8)));
typedef float    f32x4 __attribute__((ext_vector_type(4)));

#define MFMA16(a, b, c) __builtin_amdgcn_mfma_f32_16x16x32_f16((a), (b), (c), 0, 0, 0)

__device__ __forceinline__ float rcpf(float x) {
#if __has_builtin(__builtin_amdgcn_rcpf)
  return __builtin_amdgcn_rcpf(x);
#else
  return 1.0f / x;
#endif
}
__device__ __forceinline__ float sigf(float x)  { return rcpf(1.0f + __expf(-x)); }
__device__ __forceinline__ float tanhff(float x){ return 1.0f - 2.0f * rcpf(1.0f + __expf(2.0f * x)); }

template <int P>
__device__ __forceinline__ void prio() {
#if __has_builtin(__builtin_amdgcn_s_setprio)
  __builtin_amdgcn_s_setprio(P);
#endif
}
__device__ __forceinline__ void schedbar() {
#if __has_builtin(__builtin_amdgcn_sched_barrier)
  __builtin_amdgcn_sched_barrier(0);
#endif
}

__device__ __forceinline__ unsigned packf2(float lo, float hi) {
  _Float16 a = (_Float16)lo, b = (_Float16)hi;
  unsigned short ua = __builtin_bit_cast(unsigned short, a);
  unsigned short ub = __builtin_bit_cast(unsigned short, b);
  return (unsigned)ua | ((unsigned)ub << 16);
}
__device__ __forceinline__ f16x8 ld16(const _Float16* p) {
  return *reinterpret_cast<const f16x8*>(p);
}

// ---- one-shot fp32 -> fp16 weight conversion into d_ws ----
__global__ void cvt_weights(const float* __restrict__ Wx1,
                            const float* __restrict__ Wh1,
                            const float* __restrict__ Wx2,
                            const float* __restrict__ Wh2,
                            _Float16* __restrict__ W16) {
  const int P1 = oWh1 / 2, P2 = oWx2 / 2, P3 = oWh2 / 2, PE = nW / 2;
  for (int i = blockIdx.x * blockDim.x + threadIdx.x; i < PE;
       i += gridDim.x * blockDim.x) {
    const float* s; int e;
    if (i < P1)      { s = Wx1; e = i * 2; }
    else if (i < P2) { s = Wh1; e = (i - P1) * 2; }
    else if (i < P3) { s = Wx2; e = (i - P2) * 2; }
    else             { s = Wh2; e = (i - P3) * 2; }
    const float2 v = *reinterpret_cast<const float2*>(s + e);
    *reinterpret_cast<unsigned*>(W16 + (size_t)i * 2) = packf2(v.x, v.y);
  }
}

// One-layer LSTM block skeleton: 512 blocks x 256 thr (4 waves, VGPR cap 256),
// 1 chain/block -> 2 blocks/CU co-resident (independent chains overlap stalls).
// Wave w owns cells [32w, 32w+32): tiles ti = g*8 + 2w + hh for gate g, half hh.
// C/D mapping (col=lane&15, row=4*(lane>>4)+reg): lane 16q (n==0) holds all 4
// gates of cells 32w+16hh+4q+r in d[g*2+hh][r] -> in-lane activation, ONE
// barrier per step. A/B share k-chunk packing (HW k-permutation cancels).

// ---------------- K1: layer 1 ----------------
__global__ __launch_bounds__(256) void lstm_l1(
    const float* __restrict__ x, const _Float16* __restrict__ W16,
    const float* __restrict__ bx1, const float* __restrict__ bh1,
    _Float16* __restrict__ h1out)
{
  const int tid  = threadIdx.x;
  const int b    = blockIdx.x;
  const int w    = tid >> 6;
  const int lane = tid & 63;
  const int q    = lane >> 4;
  const int n    = lane & 15;

  __shared__ __align__(16) _Float16 xF[8][16][8];       // [kc][col][e] 2 KiB
  __shared__ __align__(16) _Float16 hH[2][kTT][16][8];  // [buf][dt][kc][e] 8 KiB
  __shared__ float xg[kTT][516];                        // [col][row] 33 KiB
  __shared__ float bls[512];                            // bias sums 2 KiB

  const _Float16* Wh = W16 + oWh1;
  const _Float16* Wx = W16 + oWx1;

  // resident Wh1: 8 M-tiles (a = g*2+hh), 32 frags = 128 VGPR
  f16x8 Ah[8][4];
#pragma unroll
  for (int a = 0; a < 8; ++a) {
    const int row = ((a >> 1) * 8 + 2 * w + (a & 1)) * 16 + n;
#pragma unroll
    for (int kt = 0; kt < 4; ++kt)
      Ah[a][kt] = ld16(Wh + (size_t)row * kH + kt * 32 + q * 8);
  }

  bls[tid]       = bx1[tid]       + bh1[tid];
  bls[tid + 256] = bx1[tid + 256] + bh1[tid + 256];
  if (tid < 32) {   // zero h(-1) slot: hH[1][15]
    uint2 z; z.x = 0u; z.y = 0u;
    reinterpret_cast<uint2*>(&hH[1][kTT - 1][0][0])[tid] = z;
  }
  float cst[8];
#pragma unroll
  for (int i = 0; i < 8; ++i) cst[i] = 0.f;

  for (int T = 0; T < kS / kTT; ++T) {
    {  // stage x tile (256 float4 loads, coalesced)
      const int dt = tid >> 4, k = (tid & 15) * 4;
      const float4 v = *reinterpret_cast<const float4*>(
          x + ((size_t)b * kS + (size_t)(T * kTT + dt)) * kI + k);
      uint2 p; p.x = packf2(v.x, v.y); p.y = packf2(v.z, v.w);
      *reinterpret_cast<uint2*>(&xF[k >> 3][dt][k & 7]) = p;
    }
    __syncthreads();

    {  // tile GEMM: xg[col][row] = Wx1 . x + bias (16 real cols, K=64)
      const char* xb = reinterpret_cast<const char*>(&xF[0][0][0]);
      const f16x8 bf0 = *reinterpret_cast<const f16x8*>(xb + ((q * 16 + n) << 4));
      const f16x8 bf1 = *reinterpret_cast<const f16x8*>(xb + (((4 + q) * 16 + n) << 4));
#pragma unroll
      for (int a = 0; a < 8; ++a) {
        const int g = a >> 1, hh = a & 1;
        const int wrow = (g * 8 + 2 * w + hh) * 16 + n;
        const int r0   = g * 128 + (2 * w + hh) * 16 + q * 4;
        f32x4 e = {0.f, 0.f, 0.f, 0.f};
        e = MFMA16(ld16(Wx + (size_t)wrow * kI + q * 8),      bf0, e);
        e = MFMA16(ld16(Wx + (size_t)wrow * kI + 32 + q * 8), bf1, e);
        e += *reinterpret_cast<const f32x4*>(&bls[r0]);
        *reinterpret_cast<f32x4*>(&xg[n][r0]) = e;
      }
    }
    __syncthreads();

    for (int dt = 0; dt < kTT; ++dt) {
      const char* hb = (dt == 0)
          ? reinterpret_cast<const char*>(&hH[(T + 1) & 1][kTT - 1][0][0])
          : reinterpret_cast<const char*>(&hH[T & 1][dt - 1][0][0]);
      const f16x8 bf0 = *reinterpret_cast<const f16x8*>(hb + ((0  + q) << 4));
      const f16x8 bf1 = *reinterpret_cast<const f16x8*>(hb + ((4  + q) << 4));
      const f16x8 bf2 = *reinterpret_cast<const f16x8*>(hb + ((8  + q) << 4));
      const f16x8 bf3 = *reinterpret_cast<const f16x8*>(hb + ((12 + q) << 4));

      f32x4 d[8];
      prio<1>();
#pragma unroll
      for (int a = 0; a < 8; ++a) {
        f32x4 t_ = {0.f, 0.f, 0.f, 0.f};
        t_ = MFMA16(Ah[a][0], bf0, t_);  t_ = MFMA16(Ah[a][1], bf1, t_);
        t_ = MFMA16(Ah[a][2], bf2, t_);  t_ = MFMA16(Ah[a][3], bf3, t_);
        d[a] = t_;
      }
      prio<0>();

      if (n == 0) {   // in-lane activation: 8 cells (2 halves x 4)
#pragma unroll
        for (int hh = 0; hh < 2; ++hh) {
          const int c0 = (2 * w + hh) * 16 + q * 4;
          const f32x4 xi  = *reinterpret_cast<const f32x4*>(&xg[dt][c0]);
          const f32x4 xf  = *reinterpret_cast<const f32x4*>(&xg[dt][128 + c0]);
          const f32x4 xgv = *reinterpret_cast<const f32x4*>(&xg[dt][256 + c0]);
          const f32x4 xo  = *reinterpret_cast<const f32x4*>(&xg[dt][384 + c0]);
          float h[4];
#pragma unroll
          for (int r = 0; r < 4; ++r) {
            const float gi = d[0 + hh][r] + xi[r];
            const float gf = d[2 + hh][r] + xf[r];
            const float gg = d[4 + hh][r] + xgv[r];
            const float go = d[6 + hh][r] + xo[r];
            float& cs = cst[hh * 4 + r];
            cs = sigf(gf) * cs + sigf(gi) * tanhff(gg);
            h[r] = sigf(go) * tanhff(cs);
          }
          uint2 p; p.x = packf2(h[0], h[1]); p.y = packf2(h[2], h[3]);
          *reinterpret_cast<uint2*>(&hH[T & 1][dt][c0 >> 3][c0 & 7]) = p;
        }
      }
      __syncthreads();
    }

    {  // dump tile's h to global (coalesced uint4)
      const int dt = tid >> 4, k8 = tid & 15;
      const uint4 v = reinterpret_cast<const uint4*>(&hH[T & 1][dt][0][0])[k8];
      *reinterpret_cast<uint4*>(
          h1out + ((size_t)b * kS + (size_t)(T * kTT + dt)) * kH + k8 * 8) = v;
    }
  }
}

// ---------------- K2: layer 2 + head ----------------
__global__ __launch_bounds__(256) void lstm_l2(
    const _Float16* __restrict__ h1in, const _Float16* __restrict__ W16,
    const float* __restrict__ bx2, const float* __restrict__ bh2,
    const float* __restrict__ Wc,  const float* __restrict__ bc,
    float* __restrict__ out)
{
  const int tid  = threadIdx.x;
  const int b    = blockIdx.x;
  const int w    = tid >> 6;
  const int lane = tid & 63;
  const int q    = lane >> 4;
  const int n    = lane & 15;

  __shared__ __align__(16) _Float16 h1F[16][16][8];   // [kc][col][e] 4 KiB
  __shared__ __align__(16) _Float16 h2P[2][16][8];    // parity dbuf 1 KiB
  __shared__ float xg[kTT][516];                      // 33 KiB
  __shared__ float bls[512];                          // 2 KiB
  __shared__ float hfin[128];

  const _Float16* Wh = W16 + oWh2;
  const _Float16* Wx = W16 + oWx2;

  f16x8 Ah[8][4];
#pragma unroll
  for (int a = 0; a < 8; ++a) {
    const int row = ((a >> 1) * 8 + 2 * w + (a & 1)) * 16 + n;
#pragma unroll
    for (int kt = 0; kt < 4; ++kt)
      Ah[a][kt] = ld16(Wh + (size_t)row * kH + kt * 32 + q * 8);
  }

  bls[tid]       = bx2[tid]       + bh2[tid];
  bls[tid + 256] = bx2[tid + 256] + bh2[tid + 256];
  if (tid < 64) {   // zero h2(-1) parity slot
    uint2 z; z.x = 0u; z.y = 0u;
    reinterpret_cast<uint2*>(&h2P[1][0][0])[tid] = z;
  }
  float cst[8];
#pragma unroll
  for (int i = 0; i < 8; ++i) cst[i] = 0.f;

  for (int T = 0; T < kS / kTT; ++T) {
    {  // stage h1 tile (coalesced uint4)
      const int dt = tid >> 4, k8 = tid & 15;
      const uint4 v = *reinterpret_cast<const uint4*>(
          h1in + ((size_t)b * kS + (size_t)(T * kTT + dt)) * kH + k8 * 8);
      *reinterpret_cast<uint4*>(&h1F[k8][dt][0]) = v;
    }
    __syncthreads();

    {  // tile GEMM: xg = Wx2 . h1 + bias (K=128), streamed Wx in 2 halves
      const char* xb = reinterpret_cast<const char*>(&h1F[0][0][0]);
      f16x8 bfg[4];
#pragma unroll
      for (int kt = 0; kt < 4; ++kt)
        bfg[kt] = *reinterpret_cast<const f16x8*>(xb + (((kt * 4 + q) * 16 + n) << 4));
#pragma unroll
      for (int a = 0; a < 4; ++a) {
        const int g = a >> 1, hh = a & 1;
        const int wrow = (g * 8 + 2 * w + hh) * 16 + n;
        const int r0   = g * 128 + (2 * w + hh) * 16 + q * 4;
        f32x4 e = {0.f, 0.f, 0.f, 0.f};
        e = MFMA16(ld16(Wx + (size_t)wrow * kH + q * 8),      bfg[0], e);
        e = MFMA16(ld16(Wx + (size_t)wrow * kH + 32 + q * 8), bfg[1], e);
        e = MFMA16(ld16(Wx + (size_t)wrow * kH + 64 + q * 8), bfg[2], e);
        e = MFMA16(ld16(Wx + (size_t)wrow * kH + 96 + q * 8), bfg[3], e);
        e += *reinterpret_cast<const f32x4*>(&bls[r0]);
        *reinterpret_cast<f32x4*>(&xg[n][r0]) = e;
      }
      schedbar();   // cap streamed-weight live range
#pragma unroll
      for (int a = 4; a < 8; ++a) {
        const int g = a >> 1, hh = a & 1;
        const int wrow = (g * 8 + 2 * w + hh) * 16 + n;
        const int r0   = g * 128 + (2 * w + hh) * 16 + q * 4;
        f32x4 e = {0.f, 0.f, 0.f, 0.f};
        e = MFMA16(ld16(Wx + (size_t)wrow * kH + q * 8),      bfg[0], e);
        e = MFMA16(ld16(Wx + (size_t)wrow * kH + 32 + q * 8), bfg[1], e);
        e = MFMA16(ld16(Wx + (size_t)wrow * kH + 64 + q * 8), bfg[2], e);
        e = MFMA16(ld16(Wx + (size_t)wrow * kH + 96 + q * 8), bfg[3], e);
        e += *reinterpret_cast<const f32x4*>(&bls[r0]);
        *reinterpret_cast<f32x4*>(&xg[n][r0]) = e;
      }
    }
    __syncthreads();

    for (int dt = 0; dt < kTT; ++dt) {
      const int t = T * kTT + dt;
      const char* hb = reinterpret_cast<const char*>(&h2P[(t + 1) & 1][0][0]);
      const f16x8 bf0 = *reinterpret_cast<const f16x8*>(hb + ((0  + q) << 4));
      const f16x8 bf1 = *reinterpret_cast<const f16x8*>(hb + ((4  + q) << 4));
      const f16x8 bf2 = *reinterpret_cast<const f16x8*>(hb + ((8  + q) << 4));
      const f16x8 bf3 = *reinterpret_cast<const f16x8*>(hb + ((12 + q) << 4));

      f32x4 d[8];
      prio<1>();
#pragma unroll
      for (int a = 0; a < 8; ++a) {
        f32x4 t_ = {0.f, 0.f, 0.f, 0.f};
        t_ = MFMA16(Ah[a][0], bf0, t_);  t_ = MFMA16(Ah[a][1], bf1, t_);
        t_ = MFMA16(Ah[a][2], bf2, t_);  t_ = MFMA16(Ah[a][3], bf3, t_);
        d[a] = t_;
      }
      prio<0>();

      if (n == 0) {
#pragma unroll
        for (int hh = 0; hh < 2; ++hh) {
          const int c0 = (2 * w + hh) * 16 + q * 4;
          const f32x4 xi  = *reinterpret_cast<const f32x4*>(&xg[dt][c0]);
          const f32x4 xf  = *reinterpret_cast<const f32x4*>(&xg[dt][128 + c0]);
          const f32x4 xgv = *reinterpret_cast<const f32x4*>(&xg[dt][256 + c0]);
          const f32x4 xo  = *reinterpret_cast<const f32x4*>(&xg[dt][384 + c0]);
          float h[4];
#pragma unroll
          for (int r = 0; r < 4; ++r) {
            const float gi = d[0 + hh][r] + xi[r];
            const float gf = d[2 + hh][r] + xf[r];
            const float gg = d[4 + hh][r] + xgv[r];
            const float go = d[6 + hh][r] + xo[r];
            float& cs = cst[hh * 4 + r];
            cs = sigf(gf) * cs + sigf(gi) * tanhff(gg);
            h[r] = sigf(go) * tanhff(cs);
          }
          uint2 p; p.x = packf2(h[0], h[1]); p.y = packf2(h[2], h[3]);
          *reinterpret_cast<uint2*>(&h2P[t & 1][c0 >> 3][c0 & 7]) = p;
          if (t == kS - 1) {
            f32x4 hv = {h[0], h[1], h[2], h[3]};
            *reinterpret_cast<f32x4*>(&hfin[c0]) = hv;
          }
        }
      }
      __syncthreads();
    }
  }

  // classifier head: logits[b, m] = Wc[m,:] . h2fin + bc[m]
  if (tid < 4) {
    const float* wr = Wc + (size_t)tid * kH;
    float s0 = 0.f, s1 = 0.f, s2 = 0.f, s3 = 0.f;
#pragma unroll
    for (int j = 0; j < kH; j += 4) {
      s0 = fmaf(wr[j],     hfin[j],     s0);
      s1 = fmaf(wr[j + 1], hfin[j + 1], s1);
      s2 = fmaf(wr[j + 2], hfin[j + 2], s2);
      s3 = fmaf(wr[j + 3], hfin[j + 3], s3);
    }
    out[(size_t)b * 4 + tid] = bc[tid] + ((s0 + s1) + (s2 + s3));
  }
}

} // namespace

extern "C" void kernel_launch(void* const* d_in, const int* in_sizes, int n_in,
                              void* d_out, int out_size, void* d_ws, size_t ws_size,
                              hipStream_t stream) {
  const float* x   = (const float*)d_in[0];
  const float* Wx1 = (const float*)d_in[1];
  const float* bx1 = (const float*)d_in[2];
  const float* Wh1 = (const float*)d_in[3];
  const float* bh1 = (const float*)d_in[4];
  const float* Wx2 = (const float*)d_in[5];
  const float* bx2 = (const float*)d_in[6];
  const float* Wh2 = (const float*)d_in[7];
  const float* bh2 = (const float*)d_in[8];
  const float* Wc  = (const float*)d_in[9];
  const float* bc  = (const float*)d_in[10];

  _Float16* W16 = (_Float16*)d_ws;                 // 448 KiB fp16 weights
  _Float16* h1  = (_Float16*)d_ws + nW;            // 128 MiB layer-1 stream

  hipLaunchKernelGGL(cvt_weights, dim3(448), dim3(256), 0, stream,
                     Wx1, Wh1, Wx2, Wh2, W16);
  hipLaunchKernelGGL(lstm_l1, dim3(512), dim3(256), 0, stream,
                     x, W16, bx1, bh1, h1);
  hipLaunchKernelGGL(lstm_l2, dim3(512), dim3(256), 0, stream,
                     h1, W16, bx2, bh2, Wc, bc, (float*)d_out);
}

// Round 17
// 1947.393 us; speedup vs baseline: 2.3764x; 2.3764x over previous
//
#include <hip/hip_runtime.h>
#include <hip/hip_fp16.h>

namespace {

constexpr int kS = 1024;   // SEQ
constexpr int kI = 64;     // INPUT_SIZE
constexpr int kH = 128;    // HIDDEN

// fp16 weight layout in d_ws (element offsets)
constexpr int oWx1 = 0;            // [512][64]
constexpr int oWh1 = 32768;        // [512][128]
constexpr int oWx2 = 98304;        // [512][128]
constexpr int oWh2 = 163840;       // [512][128]
constexpr int nW   = 229376;

typedef _Float16 f16x8 __attribute__((ext_vector_type(8)));
typedef float    f32x4 __attribute__((ext_vector_type(4)));

#define MFMA16(a, b, c) __builtin_amdgcn_mfma_f32_16x16x32_f16((a), (b), (c), 0, 0, 0)

__device__ __forceinline__ float rcpf(float x) {
#if __has_builtin(__builtin_amdgcn_rcpf)
  return __builtin_amdgcn_rcpf(x);
#else
  return 1.0f / x;
#endif
}
__device__ __forceinline__ float sigf(float x)  { return rcpf(1.0f + __expf(-x)); }
__device__ __forceinline__ float tanhff(float x){ return 1.0f - 2.0f * rcpf(1.0f + __expf(2.0f * x)); }

template <int P>
__device__ __forceinline__ void prio() {
#if __has_builtin(__builtin_amdgcn_s_setprio)
  __builtin_amdgcn_s_setprio(P);
#endif
}

__device__ __forceinline__ unsigned packf2(float lo, float hi) {
  _Float16 a = (_Float16)lo, b = (_Float16)hi;
  unsigned short ua = __builtin_bit_cast(unsigned short, a);
  unsigned short ub = __builtin_bit_cast(unsigned short, b);
  return (unsigned)ua | ((unsigned)ub << 16);
}
__device__ __forceinline__ f16x8 ld16(const _Float16* p) {
  return *reinterpret_cast<const f16x8*>(p);
}

// ---- one-shot fp32 -> fp16 weight conversion into d_ws ----
__global__ void cvt_weights(const float* __restrict__ Wx1,
                            const float* __restrict__ Wh1,
                            const float* __restrict__ Wx2,
                            const float* __restrict__ Wh2,
                            _Float16* __restrict__ W16) {
  const int P1 = oWh1 / 2, P2 = oWx2 / 2, P3 = oWh2 / 2, PE = nW / 2;
  for (int i = blockIdx.x * blockDim.x + threadIdx.x; i < PE;
       i += gridDim.x * blockDim.x) {
    const float* s; int e;
    if (i < P1)      { s = Wx1; e = i * 2; }
    else if (i < P2) { s = Wh1; e = (i - P1) * 2; }
    else if (i < P3) { s = Wx2; e = (i - P2) * 2; }
    else             { s = Wh2; e = (i - P3) * 2; }
    const float2 v = *reinterpret_cast<const float2*>(s + e);
    *reinterpret_cast<unsigned*>(W16 + (size_t)i * 2) = packf2(v.x, v.y);
  }
}

// Structure (both layer kernels): 256 blocks x 512 thr (8 waves, VGPR cap
// 128), chains b0,b0+1. Wave w owns tiles {g*128 + 16w} for gates g=0..3
// (cells [16w,16w+16)); Wh resident = 16 frags = 64 VGPR (round-13-proven
// no-spill budget). By the C/D mapping (col=lane&15, row=4*(lane>>4)+reg),
// lane (q, n<2) holds all 4 gates of cells 16w+4q..+3 for chain n in regs
// d0..d3 -> IN-LANE activation: no gbuf, ONE barrier per step (parity/dt
// double-buffered h). Wx handled once per 8-step tile as a real GEMM
// (16 real B-cols, bias folded), Wx frags streamed with kt-outer loop.
// A/B share k-chunk packing (HW k-permutation cancels).

// ---------------- K1: layer 1 ----------------
__global__ __launch_bounds__(512) void lstm_l1(
    const float* __restrict__ x, const _Float16* __restrict__ W16,
    const float* __restrict__ bx1, const float* __restrict__ bh1,
    _Float16* __restrict__ h1out)
{
  const int tid  = threadIdx.x;
  const int b0   = blockIdx.x * 2;
  const int w    = tid >> 6;
  const int lane = tid & 63;
  const int q    = lane >> 4;
  const int n    = lane & 15;
  const int csel = (n < 2) ? n : 0;

  __shared__ __align__(16) _Float16 xF[8][16][8];        // [kc][col][e] 2 KiB
  __shared__ __align__(16) _Float16 hH[2][8][2][16][8];  // [buf][dt][c][kc][e] 8 KiB
  __shared__ float xg[16][516];                          // [col][row] 33 KiB
  __shared__ float bls[512];                             // folded biases 2 KiB

  const _Float16* Wh = W16 + oWh1;
  const _Float16* Wx = W16 + oWx1;

  f16x8 Ah[4][4];                      // gate a, k-tile kt
#pragma unroll
  for (int a = 0; a < 4; ++a) {
    const int row = a * 128 + w * 16 + n;
#pragma unroll
    for (int kt = 0; kt < 4; ++kt)
      Ah[a][kt] = ld16(Wh + (size_t)row * kH + kt * 32 + q * 8);
  }

  bls[tid] = bx1[tid] + bh1[tid];
  if (tid < 32) {                      // zero h(-1): hH[1][7][*]
    uint4 z = {0u, 0u, 0u, 0u};
    reinterpret_cast<uint4*>(&hH[1][7][0][0][0])[tid] = z;
  }
  f32x4 cst = {0.f, 0.f, 0.f, 0.f};

  for (int T = 0; T < 128; ++T) {
    {  // stage x tile (512 float2 loads, coalesced)
      const int dt = tid >> 6, c = (tid >> 5) & 1, k2 = (tid & 31) * 2;
      const float2 v = *reinterpret_cast<const float2*>(
          x + ((size_t)(b0 + c) * kS + (size_t)(T * 8 + dt)) * kI + k2);
      *reinterpret_cast<unsigned*>(&xF[k2 >> 3][dt * 2 + c][k2 & 7]) =
          packf2(v.x, v.y);
    }
    __syncthreads();

    {  // tile GEMM: xg[col][row] = Wx1 . x + bias (K=64, kt-outer, Wx streamed)
      const char* xb = reinterpret_cast<const char*>(&xF[0][0][0]);
      f32x4 e0 = {0,0,0,0}, e1 = {0,0,0,0}, e2 = {0,0,0,0}, e3 = {0,0,0,0};
#pragma unroll
      for (int kt = 0; kt < 2; ++kt) {
        const f16x8 bf = *reinterpret_cast<const f16x8*>(
            xb + (((kt * 4 + q) * 16 + n) << 4));
        e0 = MFMA16(ld16(Wx + (size_t)(0 * 128 + w * 16 + n) * kI + kt * 32 + q * 8), bf, e0);
        e1 = MFMA16(ld16(Wx + (size_t)(1 * 128 + w * 16 + n) * kI + kt * 32 + q * 8), bf, e1);
        e2 = MFMA16(ld16(Wx + (size_t)(2 * 128 + w * 16 + n) * kI + kt * 32 + q * 8), bf, e2);
        e3 = MFMA16(ld16(Wx + (size_t)(3 * 128 + w * 16 + n) * kI + kt * 32 + q * 8), bf, e3);
      }
      const int r0 = w * 16 + q * 4;
      e0 += *reinterpret_cast<const f32x4*>(&bls[r0]);
      e1 += *reinterpret_cast<const f32x4*>(&bls[128 + r0]);
      e2 += *reinterpret_cast<const f32x4*>(&bls[256 + r0]);
      e3 += *reinterpret_cast<const f32x4*>(&bls[384 + r0]);
      *reinterpret_cast<f32x4*>(&xg[n][r0])       = e0;
      *reinterpret_cast<f32x4*>(&xg[n][128 + r0]) = e1;
      *reinterpret_cast<f32x4*>(&xg[n][256 + r0]) = e2;
      *reinterpret_cast<f32x4*>(&xg[n][384 + r0]) = e3;
      // xg rows [16w,16w+16) are produced and consumed by wave w only ->
      // no barrier needed here (in-wave LDS ordering via lgkmcnt).
    }

    for (int dt = 0; dt < 8; ++dt) {
      const char* hb = (dt == 0)
          ? reinterpret_cast<const char*>(&hH[(T + 1) & 1][7][csel][0][0])
          : reinterpret_cast<const char*>(&hH[T & 1][dt - 1][csel][0][0]);
      const f16x8 bf0 = *reinterpret_cast<const f16x8*>(hb + ((0  + q) << 4));
      const f16x8 bf1 = *reinterpret_cast<const f16x8*>(hb + ((4  + q) << 4));
      const f16x8 bf2 = *reinterpret_cast<const f16x8*>(hb + ((8  + q) << 4));
      const f16x8 bf3 = *reinterpret_cast<const f16x8*>(hb + ((12 + q) << 4));

      f32x4 d0 = {0,0,0,0}, d1 = {0,0,0,0}, d2 = {0,0,0,0}, d3 = {0,0,0,0};
      prio<1>();
      d0 = MFMA16(Ah[0][0], bf0, d0);  d1 = MFMA16(Ah[1][0], bf0, d1);
      d2 = MFMA16(Ah[2][0], bf0, d2);  d3 = MFMA16(Ah[3][0], bf0, d3);
      d0 = MFMA16(Ah[0][1], bf1, d0);  d1 = MFMA16(Ah[1][1], bf1, d1);
      d2 = MFMA16(Ah[2][1], bf1, d2);  d3 = MFMA16(Ah[3][1], bf1, d3);
      d0 = MFMA16(Ah[0][2], bf2, d0);  d1 = MFMA16(Ah[1][2], bf2, d1);
      d2 = MFMA16(Ah[2][2], bf2, d2);  d3 = MFMA16(Ah[3][2], bf2, d3);
      d0 = MFMA16(Ah[0][3], bf3, d0);  d1 = MFMA16(Ah[1][3], bf3, d1);
      d2 = MFMA16(Ah[2][3], bf3, d2);  d3 = MFMA16(Ah[3][3], bf3, d3);
      prio<0>();

      if (n < 2) {                     // in-lane activation: 4 cells, chain n
        const int col = dt * 2 + n;
        const int c0  = w * 16 + q * 4;
        const f32x4 xi  = *reinterpret_cast<const f32x4*>(&xg[col][c0]);
        const f32x4 xf_ = *reinterpret_cast<const f32x4*>(&xg[col][128 + c0]);
        const f32x4 xgv = *reinterpret_cast<const f32x4*>(&xg[col][256 + c0]);
        const f32x4 xo  = *reinterpret_cast<const f32x4*>(&xg[col][384 + c0]);
        float h[4];
#pragma unroll
        for (int r = 0; r < 4; ++r) {
          const float gi = d0[r] + xi[r];
          const float gf = d1[r] + xf_[r];
          const float gg = d2[r] + xgv[r];
          const float go = d3[r] + xo[r];
          cst[r] = sigf(gf) * cst[r] + sigf(gi) * tanhff(gg);
          h[r] = sigf(go) * tanhff(cst[r]);
        }
        uint2 p; p.x = packf2(h[0], h[1]); p.y = packf2(h[2], h[3]);
        *reinterpret_cast<uint2*>(&hH[T & 1][dt][n][c0 >> 3][c0 & 7]) = p;
      }
      __syncthreads();                 // the ONE per-step barrier
    }

    {  // dump tile's h1 to global (coalesced uint2; vmcnt drained next barrier)
      const int dt = tid >> 6, c = (tid >> 5) & 1, k = (tid & 31) * 4;
      const uint2 v = *reinterpret_cast<const uint2*>(&hH[T & 1][dt][c][k >> 3][k & 7]);
      *reinterpret_cast<uint2*>(
          h1out + ((size_t)(b0 + c) * kS + (size_t)(T * 8 + dt)) * kH + k) = v;
    }
  }
}

// ---------------- K2: layer 2 + head ----------------
__global__ __launch_bounds__(512) void lstm_l2(
    const _Float16* __restrict__ h1in, const _Float16* __restrict__ W16,
    const float* __restrict__ bx2, const float* __restrict__ bh2,
    const float* __restrict__ Wc,  const float* __restrict__ bc,
    float* __restrict__ out)
{
  const int tid  = threadIdx.x;
  const int b0   = blockIdx.x * 2;
  const int w    = tid >> 6;
  const int lane = tid & 63;
  const int q    = lane >> 4;
  const int n    = lane & 15;
  const int csel = (n < 2) ? n : 0;

  __shared__ __align__(16) _Float16 h1F[16][16][8];    // [kc][col][e] 4 KiB
  __shared__ __align__(16) _Float16 h2P[2][2][16][8];  // [par][c][kc][e] 1 KiB
  __shared__ float xg[16][516];                        // 33 KiB
  __shared__ float bls[512];                           // 2 KiB
  __shared__ float hfin[2][128];                       // 1 KiB

  const _Float16* Wh = W16 + oWh2;
  const _Float16* Wx = W16 + oWx2;

  f16x8 Ah[4][4];
#pragma unroll
  for (int a = 0; a < 4; ++a) {
    const int row = a * 128 + w * 16 + n;
#pragma unroll
    for (int kt = 0; kt < 4; ++kt)
      Ah[a][kt] = ld16(Wh + (size_t)row * kH + kt * 32 + q * 8);
  }

  bls[tid] = bx2[tid] + bh2[tid];
  if (tid < 32) {                      // zero h2(-1): h2P[1][*]
    uint4 z = {0u, 0u, 0u, 0u};
    reinterpret_cast<uint4*>(&h2P[1][0][0][0])[tid] = z;
  }
  f32x4 cst = {0.f, 0.f, 0.f, 0.f};

  for (int T = 0; T < 128; ++T) {
    {  // stage h1 tile (512 uint2 loads, coalesced)
      const int dt = tid >> 6, c = (tid >> 5) & 1, k = (tid & 31) * 4;
      const uint2 v = *reinterpret_cast<const uint2*>(
          h1in + ((size_t)(b0 + c) * kS + (size_t)(T * 8 + dt)) * kH + k);
      *reinterpret_cast<uint2*>(&h1F[k >> 3][dt * 2 + c][k & 7]) = v;
    }
    __syncthreads();

    {  // tile GEMM: xg = Wx2 . h1(tile) + bias (K=128, kt-outer, Wx streamed)
      const char* xb = reinterpret_cast<const char*>(&h1F[0][0][0]);
      f32x4 e0 = {0,0,0,0}, e1 = {0,0,0,0}, e2 = {0,0,0,0}, e3 = {0,0,0,0};
#pragma unroll
      for (int kt = 0; kt < 4; ++kt) {
        const f16x8 bf = *reinterpret_cast<const f16x8*>(
            xb + (((kt * 4 + q) * 16 + n) << 4));
        e0 = MFMA16(ld16(Wx + (size_t)(0 * 128 + w * 16 + n) * kH + kt * 32 + q * 8), bf, e0);
        e1 = MFMA16(ld16(Wx + (size_t)(1 * 128 + w * 16 + n) * kH + kt * 32 + q * 8), bf, e1);
        e2 = MFMA16(ld16(Wx + (size_t)(2 * 128 + w * 16 + n) * kH + kt * 32 + q * 8), bf, e2);
        e3 = MFMA16(ld16(Wx + (size_t)(3 * 128 + w * 16 + n) * kH + kt * 32 + q * 8), bf, e3);
      }
      const int r0 = w * 16 + q * 4;
      e0 += *reinterpret_cast<const f32x4*>(&bls[r0]);
      e1 += *reinterpret_cast<const f32x4*>(&bls[128 + r0]);
      e2 += *reinterpret_cast<const f32x4*>(&bls[256 + r0]);
      e3 += *reinterpret_cast<const f32x4*>(&bls[384 + r0]);
      *reinterpret_cast<f32x4*>(&xg[n][r0])       = e0;
      *reinterpret_cast<f32x4*>(&xg[n][128 + r0]) = e1;
      *reinterpret_cast<f32x4*>(&xg[n][256 + r0]) = e2;
      *reinterpret_cast<f32x4*>(&xg[n][384 + r0]) = e3;
    }

    for (int dt = 0; dt < 8; ++dt) {
      const int t = T * 8 + dt;
      const char* hb = reinterpret_cast<const char*>(&h2P[(t + 1) & 1][csel][0][0]);
      const f16x8 bf0 = *reinterpret_cast<const f16x8*>(hb + ((0  + q) << 4));
      const f16x8 bf1 = *reinterpret_cast<const f16x8*>(hb + ((4  + q) << 4));
      const f16x8 bf2 = *reinterpret_cast<const f16x8*>(hb + ((8  + q) << 4));
      const f16x8 bf3 = *reinterpret_cast<const f16x8*>(hb + ((12 + q) << 4));

      f32x4 d0 = {0,0,0,0}, d1 = {0,0,0,0}, d2 = {0,0,0,0}, d3 = {0,0,0,0};
      prio<1>();
      d0 = MFMA16(Ah[0][0], bf0, d0);  d1 = MFMA16(Ah[1][0], bf0, d1);
      d2 = MFMA16(Ah[2][0], bf0, d2);  d3 = MFMA16(Ah[3][0], bf0, d3);
      d0 = MFMA16(Ah[0][1], bf1, d0);  d1 = MFMA16(Ah[1][1], bf1, d1);
      d2 = MFMA16(Ah[2][1], bf1, d2);  d3 = MFMA16(Ah[3][1], bf1, d3);
      d0 = MFMA16(Ah[0][2], bf2, d0);  d1 = MFMA16(Ah[1][2], bf2, d1);
      d2 = MFMA16(Ah[2][2], bf2, d2);  d3 = MFMA16(Ah[3][2], bf2, d3);
      d0 = MFMA16(Ah[0][3], bf3, d0);  d1 = MFMA16(Ah[1][3], bf3, d1);
      d2 = MFMA16(Ah[2][3], bf3, d2);  d3 = MFMA16(Ah[3][3], bf3, d3);
      prio<0>();

      if (n < 2) {
        const int col = dt * 2 + n;
        const int c0  = w * 16 + q * 4;
        const f32x4 xi  = *reinterpret_cast<const f32x4*>(&xg[col][c0]);
        const f32x4 xf_ = *reinterpret_cast<const f32x4*>(&xg[col][128 + c0]);
        const f32x4 xgv = *reinterpret_cast<const f32x4*>(&xg[col][256 + c0]);
        const f32x4 xo  = *reinterpret_cast<const f32x4*>(&xg[col][384 + c0]);
        float h[4];
#pragma unroll
        for (int r = 0; r < 4; ++r) {
          const float gi = d0[r] + xi[r];
          const float gf = d1[r] + xf_[r];
          const float gg = d2[r] + xgv[r];
          const float go = d3[r] + xo[r];
          cst[r] = sigf(gf) * cst[r] + sigf(gi) * tanhff(gg);
          h[r] = sigf(go) * tanhff(cst[r]);
        }
        uint2 p; p.x = packf2(h[0], h[1]); p.y = packf2(h[2], h[3]);
        *reinterpret_cast<uint2*>(&h2P[t & 1][n][c0 >> 3][c0 & 7]) = p;
        if (t == kS - 1) {
          f32x4 hv = {h[0], h[1], h[2], h[3]};
          *reinterpret_cast<f32x4*>(&hfin[n][c0]) = hv;
        }
      }
      __syncthreads();
    }
  }

  // classifier head: logits[b0+c, m] = Wc[m,:] . h2fin[c] + bc[m]
  if (tid < 8) {
    const int m = tid & 3, c = tid >> 2;
    const float* wr = Wc + (size_t)m * kH;
    float s0 = 0.f, s1 = 0.f, s2 = 0.f, s3 = 0.f;
#pragma unroll
    for (int j = 0; j < kH; j += 4) {
      s0 = fmaf(wr[j],     hfin[c][j],     s0);
      s1 = fmaf(wr[j + 1], hfin[c][j + 1], s1);
      s2 = fmaf(wr[j + 2], hfin[c][j + 2], s2);
      s3 = fmaf(wr[j + 3], hfin[c][j + 3], s3);
    }
    out[(size_t)(b0 + c) * 4 + m] = bc[m] + ((s0 + s1) + (s2 + s3));
  }
}

} // namespace

extern "C" void kernel_launch(void* const* d_in, const int* in_sizes, int n_in,
                              void* d_out, int out_size, void* d_ws, size_t ws_size,
                              hipStream_t stream) {
  const float* x   = (const float*)d_in[0];
  const float* Wx1 = (const float*)d_in[1];
  const float* bx1 = (const float*)d_in[2];
  const float* Wh1 = (const float*)d_in[3];
  const float* bh1 = (const float*)d_in[4];
  const float* Wx2 = (const float*)d_in[5];
  const float* bx2 = (const float*)d_in[6];
  const float* Wh2 = (const float*)d_in[7];
  const float* bh2 = (const float*)d_in[8];
  const float* Wc  = (const float*)d_in[9];
  const float* bc  = (const float*)d_in[10];

  _Float16* W16 = (_Float16*)d_ws;          // 448 KiB fp16 weights
  _Float16* h1  = (_Float16*)d_ws + nW;     // 128 MiB layer-1 stream

  hipLaunchKernelGGL(cvt_weights, dim3(448), dim3(256), 0, stream,
                     Wx1, Wh1, Wx2, Wh2, W16);
  hipLaunchKernelGGL(lstm_l1, dim3(256), dim3(512), 0, stream,
                     x, W16, bx1, bh1, h1);
  hipLaunchKernelGGL(lstm_l2, dim3(256), dim3(512), 0, stream,
                     h1, W16, bx2, bh2, Wc, bc, (float*)d_out);
}